// Round 5
// baseline (1083.715 us; speedup 1.0000x reference)
//
#include <hip/hip_runtime.h>
#include <hip/hip_bf16.h>

#define NN 204800      // nodes
#define EE 1638400     // edges
#define BBATCH 4096    // graphs
#define NPGRAPH 50
#define KTOP 10
#define NBLK 200       // scan blocks (NN / 1024)

// converted-weight offsets (floats) inside wconv region
#define OFF_W1  0
#define OFF_W2  8192
#define OFF_W3  12288
#define OFF_B1  16384
#define OFF_B2  16448
#define OFF_B3  16512
#define OFF_WC1 16576
#define OFF_BC1 17856
#define OFF_WC2 17888
#define OFF_BC2 24032
#define OFF_WF  24096
#define OFF_BF  24736
#define WTOT    24746

__device__ __forceinline__ float bf2f(unsigned short u) {
    unsigned int x = ((unsigned int)u) << 16;
    float f; __builtin_memcpy(&f, &x, 4); return f;
}

// pack (src, coef) into one 8B record: one dirtied line per edge, not two
__device__ __forceinline__ long long pack_sc(int s, float c) {
    return ((long long)(unsigned)__float_as_int(c) << 32) | (unsigned)s;
}

// ---------------- dtype detection ----------------
// flags[0]: 1 if float tensors are fp32, 0 if bf16
// flags[1]: 1 if edge_index is int64, 0 if int32
__global__ void detect_kernel(const unsigned int* __restrict__ xw,
                              const unsigned int* __restrict__ eiw,
                              int* __restrict__ flags) {
    __shared__ int s_f32, s_i64;
    int t = threadIdx.x;
    if (t == 0) { s_f32 = 0; s_i64 = 1; }
    __syncthreads();
    unsigned w = xw[t];                       // 256 words = 512 ushorts of x
    unsigned u0 = w & 0xffffu, u1 = w >> 16;
    int e0 = (u0 >> 7) & 0xff, e1 = (u1 >> 7) & 0xff;
    // genuine bf16 N(0,1) never reaches |v| >= 512 (exp >= 0x88)
    if (e0 >= 0x88 || e1 >= 0x88) atomicOr(&s_f32, 1);
    // int64 indices < 2^31: high word of every packed pair is 0
    if (eiw[2 * t + 1] != 0) atomicAnd(&s_i64, 0);
    __syncthreads();
    if (t == 0) { flags[0] = s_f32; flags[1] = s_i64; }
}

// ---------------- weights convert (bf16 or fp32 -> fp32) ----------------

struct WPtrs { const void* p[12]; };

__global__ void convert_weights_kernel(WPtrs wp, const int* __restrict__ flags,
                                       float* __restrict__ dst) {
    const int lens[12] = {8192,4096,4096,64,64,64,1280,32,6144,64,640,10};
    const int offs[12] = {OFF_W1,OFF_W2,OFF_W3,OFF_B1,OFF_B2,OFF_B3,
                          OFF_WC1,OFF_BC1,OFF_WC2,OFF_BC2,OFF_WF,OFF_BF};
    int f32 = flags[0];
    int t = blockIdx.x * 256 + threadIdx.x;
    for (int s = 0; s < 12; ++s) {
        if (t < lens[s]) {
            float v = f32 ? ((const float*)wp.p[s])[t]
                          : bf2f(((const unsigned short*)wp.p[s])[t]);
            dst[offs[s] + t] = v;
            return;
        }
        t -= lens[s];
    }
}

// ---------------- CSR build ----------------

__global__ void zero_int_kernel(int* p, int n) {
    int i = blockIdx.x * 256 + threadIdx.x;
    if (i < n) p[i] = 0;
}

__device__ __forceinline__ int ld_idx(const void* ei, int i64, long pos) {
    return i64 ? (int)((const long long*)ei)[pos] : ((const int*)ei)[pos];
}

__global__ void count_kernel(const void* __restrict__ ei, const int* __restrict__ flags,
                             int* __restrict__ cnt) {
    int e = blockIdx.x * 256 + threadIdx.x;
    if (e >= EE) return;
    int c = ld_idx(ei, flags[1], (long)EE + e);
    atomicAdd(&cnt[c], 1);
}

// pass 1: block-local exclusive scan of (cnt[i]+1); per-block totals; dinv
__global__ __launch_bounds__(1024) void scan1_kernel(const int* __restrict__ cnt,
                                                     int* __restrict__ offs,
                                                     float* __restrict__ dinv,
                                                     int* __restrict__ blksum) {
    __shared__ int wsum[16];
    int b = blockIdx.x, t = threadIdx.x;
    int lane = t & 63, wid = t >> 6;
    int i = b * 1024 + t;
    int v = cnt[i] + 1;
    int x = v;
    #pragma unroll
    for (int d = 1; d < 64; d <<= 1) { int y = __shfl_up(x, d, 64); if (lane >= d) x += y; }
    if (lane == 63) wsum[wid] = x;
    __syncthreads();
    if (t == 0) {
        int run = 0;
        #pragma unroll
        for (int k = 0; k < 16; ++k) { int tmp = wsum[k]; wsum[k] = run; run += tmp; }
        blksum[b] = run;
    }
    __syncthreads();
    offs[i] = wsum[wid] + x - v;                 // block-local exclusive
    dinv[i] = (float)(1.0 / sqrt((double)v));    // deg = indeg + 1
}

// pass 2: exclusive scan of the 200 block sums (single block)
__global__ __launch_bounds__(256) void scan2_kernel(int* __restrict__ blksum) {
    __shared__ int wsum[4];
    int t = threadIdx.x, lane = t & 63, wid = t >> 6;
    int v = (t < NBLK) ? blksum[t] : 0;
    int x = v;
    #pragma unroll
    for (int d = 1; d < 64; d <<= 1) { int y = __shfl_up(x, d, 64); if (lane >= d) x += y; }
    if (lane == 63) wsum[wid] = x;
    __syncthreads();
    int pre = 0;
    for (int k = 0; k < wid; ++k) pre += wsum[k];
    if (t < NBLK) blksum[t] = pre + x - v;       // exclusive
}

// pass 3: add block offsets; write sentinel
__global__ __launch_bounds__(1024) void scan3_kernel(int* __restrict__ offs,
                                                     const int* __restrict__ blksum) {
    int b = blockIdx.x, i = b * 1024 + threadIdx.x;
    offs[i] += blksum[b];
    if (i == 0) offs[NN] = EE + NN;
}

__global__ void fill_self_kernel(const int* __restrict__ offs, const float* __restrict__ dinv,
                                 int* __restrict__ cursor, long long* __restrict__ epack) {
    int n = blockIdx.x * 256 + threadIdx.x;
    if (n >= NN) return;
    int p = offs[n];
    float d = dinv[n];
    __builtin_nontemporal_store(pack_sc(n, d * d), &epack[p]);
    cursor[n] = 1;
}

__global__ void fill_edges_kernel(const void* __restrict__ ei, const int* __restrict__ flags,
                                  const int* __restrict__ offs,
                                  const float* __restrict__ dinv, int* __restrict__ cursor,
                                  long long* __restrict__ epack) {
    int e = blockIdx.x * 256 + threadIdx.x;
    if (e >= EE) return;
    int i64 = flags[1];
    int r = ld_idx(ei, i64, e);
    int c = ld_idx(ei, i64, (long)EE + e);
    int p = offs[c] + atomicAdd(&cursor[c], 1);
    __builtin_nontemporal_store(pack_sc(r, dinv[r] * dinv[c]), &epack[p]);
}

// ---------------- dense XW (h = X @ W), fp32 acc ----------------
// 256 rows per block, one row per thread, acc[64]; W rows via uniform s_load.
// MODE 0: input is internal fp32. MODE 1: input dtype from flags[0].

template<int KD, int MODE>
__global__ __launch_bounds__(256) void xw_kernel(const void* __restrict__ xin_,
                                                 const int* __restrict__ flags,
                                                 int row_stride, int col_off,
                                                 const float* __restrict__ W,
                                                 float* __restrict__ hout) {
    constexpr int CH = 32;
    __shared__ float xs[256 * 36];   // f32: stride 36 floats; bf16: stride 40 ushorts
    int t = threadIdx.x;
    long row0 = (long)blockIdx.x * 256;
    bool bf16in = (MODE == 1) && (flags[0] == 0);
    float acc[64];
    #pragma unroll
    for (int c = 0; c < 64; ++c) acc[c] = 0.f;

    for (int kb = 0; kb < KD; kb += CH) {
        __syncthreads();
        if (bf16in) {
            const unsigned short* x = (const unsigned short*)xin_;
            unsigned short* xsh = (unsigned short*)xs;
            #pragma unroll
            for (int rr = 0; rr < 32; ++rr) {
                int idx = rr * 256 + t;
                int r = idx >> 5, k = idx & 31;
                xsh[r * 40 + k] = x[(row0 + r) * row_stride + col_off + kb + k];
            }
        } else {
            const float* x = (const float*)xin_;
            #pragma unroll
            for (int rr = 0; rr < 32; ++rr) {
                int idx = rr * 256 + t;
                int r = idx >> 5, k = idx & 31;
                xs[r * 36 + k] = x[(row0 + r) * row_stride + col_off + kb + k];
            }
        }
        __syncthreads();
        if (bf16in) {
            #pragma unroll 2
            for (int k = 0; k < CH; ++k) {
                float xk = bf2f(((unsigned short*)xs)[t * 40 + k]);
                const float* wr = W + (kb + k) * 64;
                #pragma unroll
                for (int c = 0; c < 64; ++c) acc[c] = fmaf(xk, wr[c], acc[c]);
            }
        } else {
            #pragma unroll 2
            for (int k = 0; k < CH; ++k) {
                float xk = xs[t * 36 + k];
                const float* wr = W + (kb + k) * 64;
                #pragma unroll
                for (int c = 0; c < 64; ++c) acc[c] = fmaf(xk, wr[c], acc[c]);
            }
        }
    }
    float* o = hout + (row0 + t) * 64;
    #pragma unroll
    for (int c = 0; c < 64; c += 4) {
        float4 v; v.x = acc[c]; v.y = acc[c+1]; v.z = acc[c+2]; v.w = acc[c+3];
        *(float4*)(o + c) = v;
    }
}

// ---------------- SpMM (+self) + bias + tanh + per-layer key max ----------------
// one wave per node; lane = feature; edge records are packed 8B (src, coef)

__global__ __launch_bounds__(256) void spmm_kernel(const float* __restrict__ h,
                                                   const int* __restrict__ offs,
                                                   const long long* __restrict__ epack,
                                                   const float* __restrict__ bias,
                                                   float* __restrict__ featOut,
                                                   float* __restrict__ keyOut) {
    int node = blockIdx.x * 4 + (threadIdx.x >> 6);
    int lane = threadIdx.x & 63;
    int j0 = offs[node], j1 = offs[node + 1];
    float acc = 0.f;
    int j = j0;
    for (; j + 3 < j1; j += 4) {
        long long e0 = __builtin_nontemporal_load(&epack[j]);
        long long e1 = __builtin_nontemporal_load(&epack[j+1]);
        long long e2 = __builtin_nontemporal_load(&epack[j+2]);
        long long e3 = __builtin_nontemporal_load(&epack[j+3]);
        int s0 = (int)(unsigned)e0, s1 = (int)(unsigned)e1;
        int s2 = (int)(unsigned)e2, s3 = (int)(unsigned)e3;
        float c0 = __int_as_float((int)(e0 >> 32)), c1 = __int_as_float((int)(e1 >> 32));
        float c2 = __int_as_float((int)(e2 >> 32)), c3 = __int_as_float((int)(e3 >> 32));
        float h0 = h[s0*64 + lane], h1 = h[s1*64 + lane];
        float h2 = h[s2*64 + lane], h3 = h[s3*64 + lane];
        acc = fmaf(h0, c0, acc); acc = fmaf(h1, c1, acc);
        acc = fmaf(h2, c2, acc); acc = fmaf(h3, c3, acc);
    }
    for (; j < j1; ++j) {
        long long e = __builtin_nontemporal_load(&epack[j]);
        int s = (int)(unsigned)e;
        float cf = __int_as_float((int)(e >> 32));
        acc = fmaf(h[s*64 + lane], cf, acc);
    }
    float val = tanhf(acc + bias[lane]);
    featOut[(long)node * 192 + lane] = val;
    float m = val;
    #pragma unroll
    for (int d = 32; d; d >>= 1) m = fmaxf(m, __shfl_xor(m, d, 64));
    if (lane == 0) keyOut[node] = m;
}

// ---------------- top-k selection per graph (key desc, index asc) ----------------

__global__ __launch_bounds__(256) void select_topk_kernel(const float* __restrict__ key3,
                                                          int* __restrict__ topidx) {
    int g = blockIdx.x * 4 + (threadIdx.x >> 6);
    int lane = threadIdx.x & 63;
    int node = g * NPGRAPH + lane;
    float k = -INFINITY;
    if (lane < NPGRAPH)
        k = fmaxf(fmaxf(key3[node], key3[NN + node]), key3[2 * NN + node]);
    for (int r = 0; r < KTOP; ++r) {
        float bk = k; int bi = lane;
        #pragma unroll
        for (int d = 32; d; d >>= 1) {
            float ok = __shfl_xor(bk, d, 64);
            int   oi = __shfl_xor(bi, d, 64);
            if (ok > bk || (ok == bk && oi < bi)) { bk = ok; bi = oi; }
        }
        if (lane == 0) topidx[g * KTOP + r] = g * NPGRAPH + bi;
        if (lane == bi) k = -INFINITY;
    }
}

// ---------------- gather + bitonic sort (values only) ----------------
// 256-key register bitonic per node (192 real + 64 +inf pads), 4 waves/block.

__global__ __launch_bounds__(256) void sort_gather_kernel(const float* __restrict__ feat,
                                                          const int* __restrict__ topidx,
                                                          float* __restrict__ pooled) {
    int lane = threadIdx.x & 63;
    int w = threadIdx.x >> 6;
    int slot = blockIdx.x * 4 + w;
    int node = topidx[slot];

    unsigned v[4];
    #pragma unroll
    for (int t = 0; t < 3; ++t) {
        float x = feat[(long)node * 192 + 64 * t + lane];
        unsigned u = __float_as_uint(x);
        v[t] = (u & 0x80000000u) ? ~u : (u | 0x80000000u);   // order-preserving key
    }
    v[3] = 0xFF800000u;   // key(+inf) pad

    // bitonic sort, element index e = 64*t + lane, ascending
    #pragma unroll
    for (int k = 2; k <= 256; k <<= 1) {
        #pragma unroll
        for (int d = 128; d >= 1; d >>= 1) {
            if (d >= k) continue;           // folds at compile time
            if (d >= 64) {
                int dt = d >> 6;
                #pragma unroll
                for (int t = 0; t < 4; ++t) {
                    if (!(t & dt)) {
                        int t2 = t | dt;
                        bool asc = ((64 * t) & k) == 0;
                        unsigned a = v[t], b = v[t2];
                        unsigned mn = a < b ? a : b;
                        unsigned mx = a < b ? b : a;
                        v[t]  = asc ? mn : mx;
                        v[t2] = asc ? mx : mn;
                    }
                }
            } else {
                #pragma unroll
                for (int t = 0; t < 4; ++t) {
                    unsigned p = (unsigned)__shfl_xor((int)v[t], d, 64);
                    int e = 64 * t + lane;
                    bool lower = (lane & d) == 0;
                    bool asc = (e & k) == 0;
                    unsigned mn = v[t] < p ? v[t] : p;
                    unsigned mx = v[t] < p ? p : v[t];
                    v[t] = (lower == asc) ? mn : mx;
                }
            }
        }
    }

    #pragma unroll
    for (int t = 0; t < 3; ++t) {
        unsigned kk = v[t];
        unsigned u = (kk & 0x80000000u) ? (kk ^ 0x80000000u) : ~kk;
        pooled[(long)slot * 192 + 64 * t + lane] = __uint_as_float(u);
    }
}

// ---------------- conv1 + relu + maxpool ----------------

__global__ __launch_bounds__(256) void conv1_kernel(const float* __restrict__ pooled,
                                                    const float* __restrict__ wc,
                                                    float* __restrict__ pool1) {
    __shared__ float p[1920];    // [10][192]
    __shared__ float w[1280];    // [32][10][4]
    __shared__ float c1[1536];   // [32][48]
    int b = blockIdx.x, t = threadIdx.x;
    for (int i = t; i < 1920; i += 256) p[i] = pooled[(long)b * 1920 + i];
    for (int i = t; i < 1280; i += 256) w[i] = wc[OFF_WC1 + i];
    __syncthreads();
    for (int o = t; o < 1536; o += 256) {
        int oc = o / 48, s = o % 48;
        float acc = wc[OFF_BC1 + oc];
        #pragma unroll
        for (int ic = 0; ic < 10; ++ic)
            #pragma unroll
            for (int t4 = 0; t4 < 4; ++t4)
                acc = fmaf(p[ic * 192 + s * 4 + t4], w[oc * 40 + ic * 4 + t4], acc);
        c1[o] = fmaxf(acc, 0.f);
    }
    __syncthreads();
    for (int o = t; o < 384; o += 256) {
        int oc = o / 12, q = o % 12;
        float m = c1[oc * 48 + q * 4];
        #pragma unroll
        for (int u = 1; u < 4; ++u) m = fmaxf(m, c1[oc * 48 + q * 4 + u]);
        pool1[(long)b * 384 + o] = m;
    }
}

// ---------------- conv2 + relu + maxpool + FC; out dtype per flags[0] ----------------

__global__ __launch_bounds__(256) void conv2_fc_kernel(const float* __restrict__ pool1,
                                                       const float* __restrict__ wc,
                                                       const int* __restrict__ flags,
                                                       void* __restrict__ outv) {
    __shared__ float p[384];     // [32][12]
    __shared__ float w2[6144];   // [64][32][3]
    __shared__ float r2[256];    // [64][4]
    __shared__ float xfs[64];
    int b = blockIdx.x, t = threadIdx.x;
    int f32o = flags[0];
    for (int i = t; i < 384; i += 256) p[i] = pool1[(long)b * 384 + i];
    for (int i = t; i < 6144; i += 256) w2[i] = wc[OFF_WC2 + i];
    __syncthreads();
    {
        int oc = t >> 2, s = t & 3;
        float acc = wc[OFF_BC2 + oc];
        #pragma unroll
        for (int ic = 0; ic < 32; ++ic)
            #pragma unroll
            for (int t3 = 0; t3 < 3; ++t3)
                acc = fmaf(p[ic * 12 + 3 * s + t3], w2[oc * 96 + ic * 3 + t3], acc);
        r2[t] = fmaxf(acc, 0.f);
    }
    __syncthreads();
    if (t < 64) {
        float m = fmaxf(fmaxf(r2[4*t], r2[4*t+1]), fmaxf(r2[4*t+2], r2[4*t+3]));
        xfs[t] = m;
        long idx = (long)BBATCH * 10 + (long)b * 64 + t;
        if (f32o) ((float*)outv)[idx] = m;
        else      ((__hip_bfloat16*)outv)[idx] = __float2bfloat16(m);
    }
    __syncthreads();
    if (t < 10) {
        float acc = wc[OFF_BF + t];
        #pragma unroll
        for (int o = 0; o < 64; ++o)
            acc = fmaf(fmaxf(xfs[o], 0.f), wc[OFF_WF + o * 10 + t], acc);
        long idx = (long)b * 10 + t;
        if (f32o) ((float*)outv)[idx] = acc;
        else      ((__hip_bfloat16*)outv)[idx] = __float2bfloat16(acc);
    }
}

// ---------------- host ----------------

extern "C" void kernel_launch(void* const* d_in, const int* in_sizes, int n_in,
                              void* d_out, int out_size, void* d_ws, size_t ws_size,
                              hipStream_t stream) {
    const void* x  = d_in[0];   // [N,128] bf16 or fp32 (detected)
    const void* ei = d_in[1];   // [2,E] int32 or int64 (detected)
    // d_in[2] = batch (structure implied, unused)
    WPtrs wp;
    wp.p[0] = d_in[3];   // W1
    wp.p[1] = d_in[5];   // W2
    wp.p[2] = d_in[7];   // W3
    wp.p[3] = d_in[4];   // b1
    wp.p[4] = d_in[6];   // b2
    wp.p[5] = d_in[8];   // b3
    wp.p[6] = d_in[9];   // Wc1
    wp.p[7] = d_in[10];  // bc1
    wp.p[8] = d_in[11];  // Wc2
    wp.p[9] = d_in[12];  // bc2
    wp.p[10] = d_in[13]; // Wf
    wp.p[11] = d_in[14]; // bf

    // ---- workspace layout (aliased; total ≈ 228 MB) ----
    char* ws = (char*)d_ws;
    size_t o = 0;
    auto take = [&](size_t bytes) { char* r = ws + o; o = (o + bytes + 255) & ~(size_t)255; return r; };
    int*       flags  = (int*)      take(2 * 4);
    float*     wconv  = (float*)    take((size_t)WTOT * 4);
    int*       offs   = (int*)      take((size_t)(NN + 1) * 4);
    long long* epack  = (long long*)take((size_t)(EE + NN) * 8);
    float*     key3   = (float*)    take((size_t)3 * NN * 4);
    int*       topidx = (int*)      take((size_t)BBATCH * KTOP * 4);
    int*       blksum = (int*)      take((size_t)NBLK * 4);
    char*      hbase  = take((size_t)NN * 64 * 4);                   // 52.4 MB, multi-purpose
    float*     feat   = (float*)    take((size_t)NN * 192 * 4);      // 157.3 MB

    float* h      = (float*)hbase;
    // aliases inside h, live only BEFORE first xw_kernel:
    int*   cnt    = (int*)(hbase);
    int*   cursor = (int*)(hbase + (1u << 20));
    float* dinv   = (float*)(hbase + (2u << 20));
    // aliases inside h, live only AFTER last spmm_kernel:
    float* pooled = (float*)(hbase);                             // 31.5 MB
    float* pool1  = (float*)(hbase + (34u << 20));               // 6.3 MB

    detect_kernel<<<1, 256, 0, stream>>>((const unsigned int*)x, (const unsigned int*)ei, flags);
    convert_weights_kernel<<<(WTOT + 255) / 256, 256, 0, stream>>>(wp, flags, wconv);
    zero_int_kernel<<<NN / 256, 256, 0, stream>>>(cnt, NN);
    count_kernel<<<EE / 256, 256, 0, stream>>>(ei, flags, cnt);
    scan1_kernel<<<NBLK, 1024, 0, stream>>>(cnt, offs, dinv, blksum);
    scan2_kernel<<<1, 256, 0, stream>>>(blksum);
    scan3_kernel<<<NBLK, 1024, 0, stream>>>(offs, blksum);
    fill_self_kernel<<<NN / 256, 256, 0, stream>>>(offs, dinv, cursor, epack);
    fill_edges_kernel<<<EE / 256, 256, 0, stream>>>(ei, flags, offs, dinv, cursor, epack);

    // layer 1
    xw_kernel<128, 1><<<NN / 256, 256, 0, stream>>>(x, flags, 128, 0, wconv + OFF_W1, h);
    spmm_kernel<<<NN / 4, 256, 0, stream>>>(h, offs, epack, wconv + OFF_B1, feat, key3);
    // layer 2
    xw_kernel<64, 0><<<NN / 256, 256, 0, stream>>>(feat, flags, 192, 0, wconv + OFF_W2, h);
    spmm_kernel<<<NN / 4, 256, 0, stream>>>(h, offs, epack, wconv + OFF_B2, feat + 64, key3 + NN);
    // layer 3
    xw_kernel<64, 0><<<NN / 256, 256, 0, stream>>>(feat, flags, 192, 64, wconv + OFF_W3, h);
    spmm_kernel<<<NN / 4, 256, 0, stream>>>(h, offs, epack, wconv + OFF_B3, feat + 128, key3 + 2 * NN);

    select_topk_kernel<<<BBATCH / 4, 256, 0, stream>>>(key3, topidx);
    sort_gather_kernel<<<BBATCH * KTOP / 4, 256, 0, stream>>>(feat, topidx, pooled);
    conv1_kernel<<<BBATCH, 256, 0, stream>>>(pooled, wconv, pool1);
    conv2_fc_kernel<<<BBATCH, 256, 0, stream>>>(pool1, wconv, flags, d_out);
}

// Round 6
// 978.833 us; speedup vs baseline: 1.1071x; 1.1071x over previous
//
#include <hip/hip_runtime.h>
#include <hip/hip_bf16.h>

#define NN 204800      // nodes
#define EE 1638400     // edges
#define BBATCH 4096    // graphs
#define NPGRAPH 50
#define KTOP 10
#define NBLK 200       // scan blocks (NN / 1024)

// converted-weight offsets (floats) inside wconv region
#define OFF_W1  0
#define OFF_W2  8192
#define OFF_W3  12288
#define OFF_B1  16384
#define OFF_B2  16448
#define OFF_B3  16512
#define OFF_WC1 16576
#define OFF_BC1 17856
#define OFF_WC2 17888
#define OFF_BC2 24032
#define OFF_WF  24096
#define OFF_BF  24736
#define WTOT    24746

__device__ __forceinline__ float bf2f(unsigned short u) {
    unsigned int x = ((unsigned int)u) << 16;
    float f; __builtin_memcpy(&f, &x, 4); return f;
}

// pack (src, coef) into one 8B record: one dirtied line per edge, not two
__device__ __forceinline__ long long pack_sc(int s, float c) {
    return ((long long)(unsigned)__float_as_int(c) << 32) | (unsigned)s;
}

// ---------------- dtype detection ----------------
// flags[0]: 1 if float tensors are fp32, 0 if bf16
// flags[1]: 1 if edge_index is int64, 0 if int32
__global__ void detect_kernel(const unsigned int* __restrict__ xw,
                              const unsigned int* __restrict__ eiw,
                              int* __restrict__ flags) {
    __shared__ int s_f32, s_i64;
    int t = threadIdx.x;
    if (t == 0) { s_f32 = 0; s_i64 = 1; }
    __syncthreads();
    unsigned w = xw[t];                       // 256 words = 512 ushorts of x
    unsigned u0 = w & 0xffffu, u1 = w >> 16;
    int e0 = (u0 >> 7) & 0xff, e1 = (u1 >> 7) & 0xff;
    // genuine bf16 N(0,1) never reaches |v| >= 512 (exp >= 0x88)
    if (e0 >= 0x88 || e1 >= 0x88) atomicOr(&s_f32, 1);
    // int64 indices < 2^31: high word of every packed pair is 0
    if (eiw[2 * t + 1] != 0) atomicAnd(&s_i64, 0);
    __syncthreads();
    if (t == 0) { flags[0] = s_f32; flags[1] = s_i64; }
}

// ---------------- weights convert (bf16 or fp32 -> fp32) ----------------

struct WPtrs { const void* p[12]; };

__global__ void convert_weights_kernel(WPtrs wp, const int* __restrict__ flags,
                                       float* __restrict__ dst) {
    const int lens[12] = {8192,4096,4096,64,64,64,1280,32,6144,64,640,10};
    const int offs[12] = {OFF_W1,OFF_W2,OFF_W3,OFF_B1,OFF_B2,OFF_B3,
                          OFF_WC1,OFF_BC1,OFF_WC2,OFF_BC2,OFF_WF,OFF_BF};
    int f32 = flags[0];
    int t = blockIdx.x * 256 + threadIdx.x;
    for (int s = 0; s < 12; ++s) {
        if (t < lens[s]) {
            float v = f32 ? ((const float*)wp.p[s])[t]
                          : bf2f(((const unsigned short*)wp.p[s])[t]);
            dst[offs[s] + t] = v;
            return;
        }
        t -= lens[s];
    }
}

// ---------------- CSR build ----------------

__global__ void zero_int_kernel(int* p, int n) {
    int i = blockIdx.x * 256 + threadIdx.x;
    if (i < n) p[i] = 0;
}

__device__ __forceinline__ int ld_idx(const void* ei, int i64, long pos) {
    return i64 ? (int)((const long long*)ei)[pos] : ((const int*)ei)[pos];
}

__global__ void count_kernel(const void* __restrict__ ei, const int* __restrict__ flags,
                             int* __restrict__ cnt) {
    int e = blockIdx.x * 256 + threadIdx.x;
    if (e >= EE) return;
    int c = ld_idx(ei, flags[1], (long)EE + e);
    atomicAdd(&cnt[c], 1);
}

// pass 1: block-local exclusive scan of (cnt[i]+1); per-block totals; dinv
__global__ __launch_bounds__(1024) void scan1_kernel(const int* __restrict__ cnt,
                                                     int* __restrict__ offs,
                                                     float* __restrict__ dinv,
                                                     int* __restrict__ blksum) {
    __shared__ int wsum[16];
    int b = blockIdx.x, t = threadIdx.x;
    int lane = t & 63, wid = t >> 6;
    int i = b * 1024 + t;
    int v = cnt[i] + 1;
    int x = v;
    #pragma unroll
    for (int d = 1; d < 64; d <<= 1) { int y = __shfl_up(x, d, 64); if (lane >= d) x += y; }
    if (lane == 63) wsum[wid] = x;
    __syncthreads();
    if (t == 0) {
        int run = 0;
        #pragma unroll
        for (int k = 0; k < 16; ++k) { int tmp = wsum[k]; wsum[k] = run; run += tmp; }
        blksum[b] = run;
    }
    __syncthreads();
    offs[i] = wsum[wid] + x - v;                 // block-local exclusive
    dinv[i] = (float)(1.0 / sqrt((double)v));    // deg = indeg + 1
}

// pass 2: exclusive scan of the 200 block sums (single block)
__global__ __launch_bounds__(256) void scan2_kernel(int* __restrict__ blksum) {
    __shared__ int wsum[4];
    int t = threadIdx.x, lane = t & 63, wid = t >> 6;
    int v = (t < NBLK) ? blksum[t] : 0;
    int x = v;
    #pragma unroll
    for (int d = 1; d < 64; d <<= 1) { int y = __shfl_up(x, d, 64); if (lane >= d) x += y; }
    if (lane == 63) wsum[wid] = x;
    __syncthreads();
    int pre = 0;
    for (int k = 0; k < wid; ++k) pre += wsum[k];
    if (t < NBLK) blksum[t] = pre + x - v;       // exclusive
}

// pass 3: add block offsets; write sentinel
__global__ __launch_bounds__(1024) void scan3_kernel(int* __restrict__ offs,
                                                     const int* __restrict__ blksum) {
    int b = blockIdx.x, i = b * 1024 + threadIdx.x;
    offs[i] += blksum[b];
    if (i == 0) offs[NN] = EE + NN;
}

__global__ void fill_self_kernel(const int* __restrict__ offs, const float* __restrict__ dinv,
                                 int* __restrict__ cursor, long long* __restrict__ epack) {
    int n = blockIdx.x * 256 + threadIdx.x;
    if (n >= NN) return;
    int p = offs[n];
    float d = dinv[n];
    __builtin_nontemporal_store(pack_sc(n, d * d), &epack[p]);
    cursor[n] = 1;
}

__global__ void fill_edges_kernel(const void* __restrict__ ei, const int* __restrict__ flags,
                                  const int* __restrict__ offs,
                                  const float* __restrict__ dinv, int* __restrict__ cursor,
                                  long long* __restrict__ epack) {
    int e = blockIdx.x * 256 + threadIdx.x;
    if (e >= EE) return;
    int i64 = flags[1];
    int r = ld_idx(ei, i64, e);
    int c = ld_idx(ei, i64, (long)EE + e);
    int p = offs[c] + atomicAdd(&cursor[c], 1);
    __builtin_nontemporal_store(pack_sc(r, dinv[r] * dinv[c]), &epack[p]);
}

// ---------------- dense XW (h = X @ W), fp32 acc ----------------
// 256 rows per block, one row per thread, acc[64]; W rows via uniform s_load.
// MODE 0: input is internal fp32. MODE 1: input dtype from flags[0].

template<int KD, int MODE>
__global__ __launch_bounds__(256) void xw_kernel(const void* __restrict__ xin_,
                                                 const int* __restrict__ flags,
                                                 int row_stride, int col_off,
                                                 const float* __restrict__ W,
                                                 float* __restrict__ hout) {
    constexpr int CH = 32;
    __shared__ float xs[256 * 36];   // f32: stride 36 floats; bf16: stride 40 ushorts
    int t = threadIdx.x;
    long row0 = (long)blockIdx.x * 256;
    bool bf16in = (MODE == 1) && (flags[0] == 0);
    float acc[64];
    #pragma unroll
    for (int c = 0; c < 64; ++c) acc[c] = 0.f;

    for (int kb = 0; kb < KD; kb += CH) {
        __syncthreads();
        if (bf16in) {
            const unsigned short* x = (const unsigned short*)xin_;
            unsigned short* xsh = (unsigned short*)xs;
            #pragma unroll
            for (int rr = 0; rr < 32; ++rr) {
                int idx = rr * 256 + t;
                int r = idx >> 5, k = idx & 31;
                xsh[r * 40 + k] = x[(row0 + r) * row_stride + col_off + kb + k];
            }
        } else {
            const float* x = (const float*)xin_;
            #pragma unroll
            for (int rr = 0; rr < 32; ++rr) {
                int idx = rr * 256 + t;
                int r = idx >> 5, k = idx & 31;
                xs[r * 36 + k] = x[(row0 + r) * row_stride + col_off + kb + k];
            }
        }
        __syncthreads();
        if (bf16in) {
            #pragma unroll 2
            for (int k = 0; k < CH; ++k) {
                float xk = bf2f(((unsigned short*)xs)[t * 40 + k]);
                const float* wr = W + (kb + k) * 64;
                #pragma unroll
                for (int c = 0; c < 64; ++c) acc[c] = fmaf(xk, wr[c], acc[c]);
            }
        } else {
            #pragma unroll 2
            for (int k = 0; k < CH; ++k) {
                float xk = xs[t * 36 + k];
                const float* wr = W + (kb + k) * 64;
                #pragma unroll
                for (int c = 0; c < 64; ++c) acc[c] = fmaf(xk, wr[c], acc[c]);
            }
        }
    }
    float* o = hout + (row0 + t) * 64;
    #pragma unroll
    for (int c = 0; c < 64; c += 4) {
        float4 v; v.x = acc[c]; v.y = acc[c+1]; v.z = acc[c+2]; v.w = acc[c+3];
        *(float4*)(o + c) = v;
    }
}

// ---------------- SpMM (+self) + bias + tanh + per-layer key max ----------------
// one wave per node; lane = feature.
// Wave cooperatively loads up to 64 packed edge records in ONE coalesced load,
// then broadcasts each via shuffle (VALU) and streams the h-gathers unroll-8:
// no load->load dependency, ~deg gathers in flight per wave.

__global__ __launch_bounds__(256) void spmm_kernel(const float* __restrict__ h,
                                                   const int* __restrict__ offs,
                                                   const long long* __restrict__ epack,
                                                   const float* __restrict__ bias,
                                                   float* __restrict__ featOut,
                                                   float* __restrict__ keyOut) {
    int node = blockIdx.x * 4 + (threadIdx.x >> 6);
    int lane = threadIdx.x & 63;
    int j0 = offs[node], j1 = offs[node + 1];
    float acc = 0.f;

    for (int base = j0; base < j1; base += 64) {
        int n = j1 - base; if (n > 64) n = 64;
        long long my = 0;
        if (lane < n) my = epack[base + lane];   // coalesced 512B wave load

        int m = 0;
        for (; m + 8 <= n; m += 8) {
            float hv[8], cf[8];
            #pragma unroll
            for (int u = 0; u < 8; ++u) {
                long long e = __shfl(my, m + u, 64);
                int s = (int)(unsigned)e;
                cf[u] = __int_as_float((int)(e >> 32));
                hv[u] = h[(long)s * 64 + lane];
            }
            #pragma unroll
            for (int u = 0; u < 8; ++u) acc = fmaf(hv[u], cf[u], acc);
        }
        for (; m < n; ++m) {
            long long e = __shfl(my, m, 64);
            int s = (int)(unsigned)e;
            float cf = __int_as_float((int)(e >> 32));
            acc = fmaf(h[(long)s * 64 + lane], cf, acc);
        }
    }

    float val = tanhf(acc + bias[lane]);
    featOut[(long)node * 192 + lane] = val;
    float m = val;
    #pragma unroll
    for (int d = 32; d; d >>= 1) m = fmaxf(m, __shfl_xor(m, d, 64));
    if (lane == 0) keyOut[node] = m;
}

// ---------------- top-k selection per graph (key desc, index asc) ----------------

__global__ __launch_bounds__(256) void select_topk_kernel(const float* __restrict__ key3,
                                                          int* __restrict__ topidx) {
    int g = blockIdx.x * 4 + (threadIdx.x >> 6);
    int lane = threadIdx.x & 63;
    int node = g * NPGRAPH + lane;
    float k = -INFINITY;
    if (lane < NPGRAPH)
        k = fmaxf(fmaxf(key3[node], key3[NN + node]), key3[2 * NN + node]);
    for (int r = 0; r < KTOP; ++r) {
        float bk = k; int bi = lane;
        #pragma unroll
        for (int d = 32; d; d >>= 1) {
            float ok = __shfl_xor(bk, d, 64);
            int   oi = __shfl_xor(bi, d, 64);
            if (ok > bk || (ok == bk && oi < bi)) { bk = ok; bi = oi; }
        }
        if (lane == 0) topidx[g * KTOP + r] = g * NPGRAPH + bi;
        if (lane == bi) k = -INFINITY;
    }
}

// ---------------- gather + bitonic sort (values only) ----------------
// 256-key register bitonic per node (192 real + 64 +inf pads), 4 waves/block.

__global__ __launch_bounds__(256) void sort_gather_kernel(const float* __restrict__ feat,
                                                          const int* __restrict__ topidx,
                                                          float* __restrict__ pooled) {
    int lane = threadIdx.x & 63;
    int w = threadIdx.x >> 6;
    int slot = blockIdx.x * 4 + w;
    int node = topidx[slot];

    unsigned v[4];
    #pragma unroll
    for (int t = 0; t < 3; ++t) {
        float x = feat[(long)node * 192 + 64 * t + lane];
        unsigned u = __float_as_uint(x);
        v[t] = (u & 0x80000000u) ? ~u : (u | 0x80000000u);   // order-preserving key
    }
    v[3] = 0xFF800000u;   // key(+inf) pad

    // bitonic sort, element index e = 64*t + lane, ascending
    #pragma unroll
    for (int k = 2; k <= 256; k <<= 1) {
        #pragma unroll
        for (int d = 128; d >= 1; d >>= 1) {
            if (d >= k) continue;           // folds at compile time
            if (d >= 64) {
                int dt = d >> 6;
                #pragma unroll
                for (int t = 0; t < 4; ++t) {
                    if (!(t & dt)) {
                        int t2 = t | dt;
                        bool asc = ((64 * t) & k) == 0;
                        unsigned a = v[t], b = v[t2];
                        unsigned mn = a < b ? a : b;
                        unsigned mx = a < b ? b : a;
                        v[t]  = asc ? mn : mx;
                        v[t2] = asc ? mx : mn;
                    }
                }
            } else {
                #pragma unroll
                for (int t = 0; t < 4; ++t) {
                    unsigned p = (unsigned)__shfl_xor((int)v[t], d, 64);
                    int e = 64 * t + lane;
                    bool lower = (lane & d) == 0;
                    bool asc = (e & k) == 0;
                    unsigned mn = v[t] < p ? v[t] : p;
                    unsigned mx = v[t] < p ? p : v[t];
                    v[t] = (lower == asc) ? mn : mx;
                }
            }
        }
    }

    #pragma unroll
    for (int t = 0; t < 3; ++t) {
        unsigned kk = v[t];
        unsigned u = (kk & 0x80000000u) ? (kk ^ 0x80000000u) : ~kk;
        pooled[(long)slot * 192 + 64 * t + lane] = __uint_as_float(u);
    }
}

// ---------------- conv1 + relu + maxpool ----------------

__global__ __launch_bounds__(256) void conv1_kernel(const float* __restrict__ pooled,
                                                    const float* __restrict__ wc,
                                                    float* __restrict__ pool1) {
    __shared__ float p[1920];    // [10][192]
    __shared__ float w[1280];    // [32][10][4]
    __shared__ float c1[1536];   // [32][48]
    int b = blockIdx.x, t = threadIdx.x;
    for (int i = t; i < 1920; i += 256) p[i] = pooled[(long)b * 1920 + i];
    for (int i = t; i < 1280; i += 256) w[i] = wc[OFF_WC1 + i];
    __syncthreads();
    for (int o = t; o < 1536; o += 256) {
        int oc = o / 48, s = o % 48;
        float acc = wc[OFF_BC1 + oc];
        #pragma unroll
        for (int ic = 0; ic < 10; ++ic)
            #pragma unroll
            for (int t4 = 0; t4 < 4; ++t4)
                acc = fmaf(p[ic * 192 + s * 4 + t4], w[oc * 40 + ic * 4 + t4], acc);
        c1[o] = fmaxf(acc, 0.f);
    }
    __syncthreads();
    for (int o = t; o < 384; o += 256) {
        int oc = o / 12, q = o % 12;
        float m = c1[oc * 48 + q * 4];
        #pragma unroll
        for (int u = 1; u < 4; ++u) m = fmaxf(m, c1[oc * 48 + q * 4 + u]);
        pool1[(long)b * 384 + o] = m;
    }
}

// ---------------- conv2 + relu + maxpool + FC; out dtype per flags[0] ----------------

__global__ __launch_bounds__(256) void conv2_fc_kernel(const float* __restrict__ pool1,
                                                       const float* __restrict__ wc,
                                                       const int* __restrict__ flags,
                                                       void* __restrict__ outv) {
    __shared__ float p[384];     // [32][12]
    __shared__ float w2[6144];   // [64][32][3]
    __shared__ float r2[256];    // [64][4]
    __shared__ float xfs[64];
    int b = blockIdx.x, t = threadIdx.x;
    int f32o = flags[0];
    for (int i = t; i < 384; i += 256) p[i] = pool1[(long)b * 384 + i];
    for (int i = t; i < 6144; i += 256) w2[i] = wc[OFF_WC2 + i];
    __syncthreads();
    {
        int oc = t >> 2, s = t & 3;
        float acc = wc[OFF_BC2 + oc];
        #pragma unroll
        for (int ic = 0; ic < 32; ++ic)
            #pragma unroll
            for (int t3 = 0; t3 < 3; ++t3)
                acc = fmaf(p[ic * 12 + 3 * s + t3], w2[oc * 96 + ic * 3 + t3], acc);
        r2[t] = fmaxf(acc, 0.f);
    }
    __syncthreads();
    if (t < 64) {
        float m = fmaxf(fmaxf(r2[4*t], r2[4*t+1]), fmaxf(r2[4*t+2], r2[4*t+3]));
        xfs[t] = m;
        long idx = (long)BBATCH * 10 + (long)b * 64 + t;
        if (f32o) ((float*)outv)[idx] = m;
        else      ((__hip_bfloat16*)outv)[idx] = __float2bfloat16(m);
    }
    __syncthreads();
    if (t < 10) {
        float acc = wc[OFF_BF + t];
        #pragma unroll
        for (int o = 0; o < 64; ++o)
            acc = fmaf(fmaxf(xfs[o], 0.f), wc[OFF_WF + o * 10 + t], acc);
        long idx = (long)b * 10 + t;
        if (f32o) ((float*)outv)[idx] = acc;
        else      ((__hip_bfloat16*)outv)[idx] = __float2bfloat16(acc);
    }
}

// ---------------- host ----------------

extern "C" void kernel_launch(void* const* d_in, const int* in_sizes, int n_in,
                              void* d_out, int out_size, void* d_ws, size_t ws_size,
                              hipStream_t stream) {
    const void* x  = d_in[0];   // [N,128] bf16 or fp32 (detected)
    const void* ei = d_in[1];   // [2,E] int32 or int64 (detected)
    // d_in[2] = batch (structure implied, unused)
    WPtrs wp;
    wp.p[0] = d_in[3];   // W1
    wp.p[1] = d_in[5];   // W2
    wp.p[2] = d_in[7];   // W3
    wp.p[3] = d_in[4];   // b1
    wp.p[4] = d_in[6];   // b2
    wp.p[5] = d_in[8];   // b3
    wp.p[6] = d_in[9];   // Wc1
    wp.p[7] = d_in[10];  // bc1
    wp.p[8] = d_in[11];  // Wc2
    wp.p[9] = d_in[12];  // bc2
    wp.p[10] = d_in[13]; // Wf
    wp.p[11] = d_in[14]; // bf

    // ---- workspace layout (aliased; total ≈ 228 MB) ----
    char* ws = (char*)d_ws;
    size_t o = 0;
    auto take = [&](size_t bytes) { char* r = ws + o; o = (o + bytes + 255) & ~(size_t)255; return r; };
    int*       flags  = (int*)      take(2 * 4);
    float*     wconv  = (float*)    take((size_t)WTOT * 4);
    int*       offs   = (int*)      take((size_t)(NN + 1) * 4);
    long long* epack  = (long long*)take((size_t)(EE + NN) * 8);
    float*     key3   = (float*)    take((size_t)3 * NN * 4);
    int*       topidx = (int*)      take((size_t)BBATCH * KTOP * 4);
    int*       blksum = (int*)      take((size_t)NBLK * 4);
    char*      hbase  = take((size_t)NN * 64 * 4);                   // 52.4 MB, multi-purpose
    float*     feat   = (float*)    take((size_t)NN * 192 * 4);      // 157.3 MB

    float* h      = (float*)hbase;
    // aliases inside h, live only BEFORE first xw_kernel:
    int*   cnt    = (int*)(hbase);
    int*   cursor = (int*)(hbase + (1u << 20));
    float* dinv   = (float*)(hbase + (2u << 20));
    // aliases inside h, live only AFTER last spmm_kernel:
    float* pooled = (float*)(hbase);                             // 31.5 MB
    float* pool1  = (float*)(hbase + (34u << 20));               // 6.3 MB

    detect_kernel<<<1, 256, 0, stream>>>((const unsigned int*)x, (const unsigned int*)ei, flags);
    convert_weights_kernel<<<(WTOT + 255) / 256, 256, 0, stream>>>(wp, flags, wconv);
    zero_int_kernel<<<NN / 256, 256, 0, stream>>>(cnt, NN);
    count_kernel<<<EE / 256, 256, 0, stream>>>(ei, flags, cnt);
    scan1_kernel<<<NBLK, 1024, 0, stream>>>(cnt, offs, dinv, blksum);
    scan2_kernel<<<1, 256, 0, stream>>>(blksum);
    scan3_kernel<<<NBLK, 1024, 0, stream>>>(offs, blksum);
    fill_self_kernel<<<NN / 256, 256, 0, stream>>>(offs, dinv, cursor, epack);
    fill_edges_kernel<<<EE / 256, 256, 0, stream>>>(ei, flags, offs, dinv, cursor, epack);

    // layer 1
    xw_kernel<128, 1><<<NN / 256, 256, 0, stream>>>(x, flags, 128, 0, wconv + OFF_W1, h);
    spmm_kernel<<<NN / 4, 256, 0, stream>>>(h, offs, epack, wconv + OFF_B1, feat, key3);
    // layer 2
    xw_kernel<64, 0><<<NN / 256, 256, 0, stream>>>(feat, flags, 192, 0, wconv + OFF_W2, h);
    spmm_kernel<<<NN / 4, 256, 0, stream>>>(h, offs, epack, wconv + OFF_B2, feat + 64, key3 + NN);
    // layer 3
    xw_kernel<64, 0><<<NN / 256, 256, 0, stream>>>(feat, flags, 192, 64, wconv + OFF_W3, h);
    spmm_kernel<<<NN / 4, 256, 0, stream>>>(h, offs, epack, wconv + OFF_B3, feat + 128, key3 + 2 * NN);

    select_topk_kernel<<<BBATCH / 4, 256, 0, stream>>>(key3, topidx);
    sort_gather_kernel<<<BBATCH * KTOP / 4, 256, 0, stream>>>(feat, topidx, pooled);
    conv1_kernel<<<BBATCH, 256, 0, stream>>>(pooled, wconv, pool1);
    conv2_fc_kernel<<<BBATCH, 256, 0, stream>>>(pool1, wconv, flags, d_out);
}